// Round 6
// baseline (58818.915 us; speedup 1.0000x reference)
//
#include <hip/hip_runtime.h>
#include <stdint.h>
#include <math.h>

#define NBLK 128
#define NTHR 256
#define Bn 16
#define Tn 2000
#define Cn 128
#define Gn 512
#define Hn 512
#define Vn 256

// ws: first 4096 B = per-group sync (16 groups x 64 u32; group g at g*256 B):
//   u32[0]  = ctrH : monotonic arrival counter, h-exchange barriers
//   u32[32] = ctrP : monotonic arrival counter, PL-ready barriers (128B apart)
// Then doubles per group (stride 3072): H0[0,512) H1[512,1024) PL[1024,3072)
#define WS_DBL_BASE 512
#define GRP_STRIDE  3072

#define OUT_SAMP ((size_t)Bn*Tn*Vn)          // 8,192,000
#define OUT_HF   (OUT_SAMP + (size_t)Bn*Tn)  // 8,224,000

typedef __attribute__((ext_vector_type(2))) double d2_t;

__device__ __forceinline__ unsigned rotl32(unsigned v, int n) {
  return (v << n) | (v >> (32 - n));
}

// JAX threefry2x32, 20 rounds, exact.
__device__ __forceinline__ void threefry2x32(unsigned k0, unsigned k1,
                                             unsigned c0, unsigned c1,
                                             unsigned& o0, unsigned& o1) {
  unsigned ks2 = k0 ^ k1 ^ 0x1BD11BDAu;
  unsigned x0 = c0 + k0;
  unsigned x1 = c1 + k1;
#define TF_R(r) { x0 += x1; x1 = rotl32(x1, r); x1 ^= x0; }
  TF_R(13) TF_R(15) TF_R(26) TF_R(6)
  x0 += k1;  x1 += ks2 + 1u;
  TF_R(17) TF_R(29) TF_R(16) TF_R(24)
  x0 += ks2; x1 += k0 + 2u;
  TF_R(13) TF_R(15) TF_R(26) TF_R(6)
  x0 += k0;  x1 += k1 + 3u;
  TF_R(17) TF_R(29) TF_R(16) TF_R(24)
  x0 += k1;  x1 += ks2 + 4u;
  TF_R(13) TF_R(15) TF_R(26) TF_R(6)
  x0 += ks2; x1 += k0 + 5u;
#undef TF_R
  o0 = x0; o1 = x1;
}

// exact JAX partitionable gumbel for step key (kt0,kt1), flat index f
__device__ __forceinline__ double jax_gumbel(unsigned kt0, unsigned kt1,
                                             unsigned f) {
  unsigned r0, r1;
  threefry2x32(kt0, kt1, 0u, f, r0, r1);
  unsigned bits = r0 ^ r1;
  float uf = __uint_as_float((bits >> 9) | 0x3f800000u) - 1.0f;
  if (uf <= 0.f) uf = 1.17549435e-38f;  // np.finfo(float32).tiny
  return -log(-log((double)uf));
}

// ---- cross-block traffic: system-scope (sc0 sc1) — PROVEN semantics.
// (r1/r4 measured: sc0-only scope is NOT sufficient for 8-block groups.)
// Multi-load asm blocks use "=&v" early-clobber (r2 lesson: plain "=v" let
// an output land on an address register of a later load -> memory fault).
__device__ __forceinline__ void st_d(double* p, double v) {
  asm volatile("global_store_dwordx2 %0, %1, off sc0 sc1"
               :: "v"(p), "v"(v) : "memory");
}
__device__ __forceinline__ d2_t ld_d2(const double* p) {
  d2_t r;
  asm volatile("global_load_dwordx4 %0, %1, off sc0 sc1\n\t"
               "s_waitcnt vmcnt(0)" : "=&v"(r) : "v"(p));
  return r;
}
__device__ __forceinline__ void ld8(const double* pl, int v, double* o) {
  const double* a0 = pl + v;
  const double* a1 = pl + 512 + v;
  const double* a2 = pl + 1024 + v;
  const double* a3 = pl + 1536 + v;
  double o0, o1, o2, o3, o4, o5, o6, o7;
  asm volatile(
    "global_load_dwordx2 %[r0], %[p0], off sc0 sc1\n\t"
    "global_load_dwordx2 %[r1], %[p0], off offset:2048 sc0 sc1\n\t"
    "global_load_dwordx2 %[r2], %[p1], off sc0 sc1\n\t"
    "global_load_dwordx2 %[r3], %[p1], off offset:2048 sc0 sc1\n\t"
    "global_load_dwordx2 %[r4], %[p2], off sc0 sc1\n\t"
    "global_load_dwordx2 %[r5], %[p2], off offset:2048 sc0 sc1\n\t"
    "global_load_dwordx2 %[r6], %[p3], off sc0 sc1\n\t"
    "global_load_dwordx2 %[r7], %[p3], off offset:2048 sc0 sc1\n\t"
    "s_waitcnt vmcnt(0)"
    : [r0]"=&v"(o0), [r1]"=&v"(o1), [r2]"=&v"(o2), [r3]"=&v"(o3),
      [r4]"=&v"(o4), [r5]"=&v"(o5), [r6]"=&v"(o6), [r7]"=&v"(o7)
    : [p0]"v"(a0), [p1]"v"(a1), [p2]"v"(a2), [p3]"v"(a3));
  o[0]=o0; o[1]=o1; o[2]=o2; o[3]=o3; o[4]=o4; o[5]=o5; o[6]=o6; o[7]=o7;
}
__device__ __forceinline__ unsigned ld_u(const unsigned* p) {
  unsigned r;
  asm volatile("global_load_dword %0, %1, off sc0 sc1\n\t"
               "s_waitcnt vmcnt(0)" : "=&v"(r) : "v"(p) : "memory");
  return r;
}

// ---- 8-way group barrier via monotonic arrival counter (r5, PROVEN) ----
__device__ __forceinline__ void gar(unsigned* ctr) {
  asm volatile("s_waitcnt vmcnt(0)" ::: "memory");
  __syncthreads();
  if (threadIdx.x == 0) atomicAdd(ctr, 1u);
}
__device__ __forceinline__ void gwt(unsigned* ctr, unsigned target) {
  if (threadIdx.x == 0) {
    int guard = 0;
    while (ld_u(ctr) < target) {
      if (++guard > 5000000) break;  // safety: never hang the bench
    }
  }
  asm volatile("" ::: "memory");
  __syncthreads();
}

extern "C" __global__ __launch_bounds__(NTHR)
void wavernn_pipe(const float* __restrict__ cond, const float* __restrict__ h0,
                  const float* __restrict__ W_ih, const float* __restrict__ W_hh,
                  const float* __restrict__ b_ih, const float* __restrict__ b_hh,
                  const float* __restrict__ W_hid, const float* __restrict__ b_hid,
                  const float* __restrict__ W_out, const float* __restrict__ b_out,
                  const float* __restrict__ emb,
                  float* __restrict__ out, double* __restrict__ ws) {
  const int tid = threadIdx.x;
  const int blk = blockIdx.x;
  const int g = blk >> 3;   // batch element (group)
  const int j = blk & 7;    // slot; slot-major => weight slice j is XCD-local
  const int lane = tid & 63, wv = tid >> 6;
  const int r8 = lane >> 3;       // row-within-batch (8 rows per instruction)
  const int c8 = lane & 7;        // k-chunk lane (8 lanes span one row's k)

  unsigned* ctrH = ((unsigned*)ws) + (size_t)g * 64;       // h barriers
  unsigned* ctrP = ((unsigned*)ws) + (size_t)g * 64 + 32;  // PL barriers
  double* G   = ws + WS_DBL_BASE + (size_t)g * GRP_STRIDE;
  double* Hb0 = G;
  double* Hb1 = G + 512;
  double* PL  = G + 1024;   // 8 x 256 partial logits

  __shared__ __attribute__((aligned(32))) double s_x[Cn];
  __shared__ __attribute__((aligned(32))) double s_h[Gn];
  __shared__ __attribute__((aligned(32))) double s_hid[64];
  __shared__ double s_hg[3][64];     // W_hh row sums (r,z,n) for block's rows
  __shared__ double s_xg[3][64];     // W_ih row sums
  __shared__ double s_hidraw[64];
  __shared__ double s_gum[256];
  __shared__ float  s_cond[Cn];
  __shared__ double s_pv[4];
  __shared__ int    s_pi[4];

  // ---- per-thread constants (biases are t-invariant; combine = wave 0) ----
  const int rrow = j * 64 + lane;
  double bih_r = 0., bih_z = 0., bih_n = 0.;
  double bhh_r = 0., bhh_z = 0., bhh_n = 0.;
  if (wv == 0) {
    bih_r = (double)b_ih[rrow]; bih_z = (double)b_ih[512 + rrow];
    bih_n = (double)b_ih[1024 + rrow];
    bhh_r = (double)b_hh[rrow]; bhh_z = (double)b_hh[512 + rrow];
    bhh_n = (double)b_hh[1024 + rrow];
  }
  const double bout_reg = (double)b_out[tid];

  // ---- init: H0 slice <- h0; x0 = cond[:,0,:] + emb[128] ----
  if (tid < 64) st_d(&Hb0[j * 64 + tid],
                     (double)h0[(size_t)g * Gn + j * 64 + tid]);
  if (tid < Cn) s_x[tid] = (double)cond[(size_t)g * Tn * Cn + tid]
                         + (double)emb[128 * Cn + tid];
  gar(ctrH); gwt(ctrH, 8u);
  ((d2_t*)s_h)[tid] = ld_d2(Hb0 + 2 * tid);   // s_h = h_0
  __syncthreads();

  for (int t = 0; t < Tn; ++t) {
    double* hnxt = (t & 1) ? Hb0 : Hb1;       // buffer for h_{t+1}

    // ===== WINDOW (overlaps in-flight PL_{t-1} round trip) =====
    // waves 0-2: W_hh dots, gate=wv, rows j*64..j*64+63.
    // k-major lanes: 8 lanes span a row's k -> one wave load = 8 rows x 1
    // line = 8 L1 transactions (vs 64 row-per-lane). acc[8] rows per lane;
    // h chunk loaded once per kk from LDS (broadcast across row groups).
    if (wv <= 2) {
      const float* lptr = W_hh + (size_t)(wv * 512 + j * 64 + r8) * Gn + c8 * 4;
      const double4* h4 = (const double4*)s_h;
      double acc[8];
#pragma unroll
      for (int b = 0; b < 8; ++b) acc[b] = 0.;
#pragma unroll 4
      for (int kk = 0; kk < 16; ++kk) {
        const double4 hv = h4[kk * 8 + c8];
#pragma unroll
        for (int b = 0; b < 8; ++b) {
          const float4 w = *(const float4*)(lptr + (size_t)b * 8 * Gn + kk * 32);
          acc[b] = fma((double)w.x, hv.x, acc[b]);
          acc[b] = fma((double)w.y, hv.y, acc[b]);
          acc[b] = fma((double)w.z, hv.z, acc[b]);
          acc[b] = fma((double)w.w, hv.w, acc[b]);
        }
      }
#pragma unroll
      for (int b = 0; b < 8; ++b) {
        acc[b] += __shfl_xor(acc[b], 1, 64);
        acc[b] += __shfl_xor(acc[b], 2, 64);
        acc[b] += __shfl_xor(acc[b], 4, 64);
        if (c8 == 0) s_hg[wv][b * 8 + r8] = acc[b];
      }
    } else {
      // wave 3: stage cond[:,t,:] ; gumbel for step t-1 (consumed at resolve)
      const int c0 = 2 * lane;
      s_cond[c0]     = cond[((size_t)g * Tn + t) * Cn + c0];
      s_cond[c0 + 1] = cond[((size_t)g * Tn + t) * Cn + c0 + 1];
      if (t > 0) {
        unsigned kt0, kt1;
        threefry2x32(0u, 1u, 0u, (unsigned)(t - 1), kt0, kt1);
#pragma unroll
        for (int i = 0; i < 4; ++i) {
          int v = 4 * lane + i;
          s_gum[v] = jax_gumbel(kt0, kt1, (unsigned)(g * Vn + v));
        }
      }
    }

    // ===== PL wait + resolve of step t-1 (byte-identical to r5) =====
    if (t > 0) {
      gwt(ctrP, (unsigned)(8 * t));        // PL_{t-1} ready
      const int v = tid;
      double l[8];
      ld8(PL, v, l);
      double logit = ((((((((l[0] + l[1]) + l[2]) + l[3]) + l[4]) + l[5])
                       + l[6]) + l[7])) + bout_reg;
      if (j == 0)
        out[(size_t)g * Tn * Vn + (size_t)(t - 1) * Vn + v] = (float)logit;
      double bv = logit + s_gum[v];
      int bi = v;
#pragma unroll
      for (int off = 1; off < 64; off <<= 1) {
        double ov = __shfl_xor(bv, off, 64);
        int oi = __shfl_xor(bi, off, 64);
        if (ov > bv || (ov == bv && oi < bi)) { bv = ov; bi = oi; }
      }
      if (lane == 0) { s_pv[wv] = bv; s_pi[wv] = bi; }
      __syncthreads();
      double fv = s_pv[0]; int fi = s_pi[0];
#pragma unroll
      for (int w = 1; w < 4; ++w) {
        double ov = s_pv[w]; int oi = s_pi[w];
        if (ov > fv || (ov == fv && oi < fi)) { fv = ov; fi = oi; }
      }
      const int samp = fi;
      if (tid == 0 && j == 0)
        out[OUT_SAMP + (size_t)g * Tn + (t - 1)] = (float)samp;
      if (tid < Cn)
        s_x[tid] = (double)s_cond[tid] + (double)emb[(size_t)samp * Cn + tid];
      __syncthreads();
    } else {
      __syncthreads();  // order window LDS writes vs x-phase reads
    }

    // ===== x-phase: W_ih dots (waves 0-2, gate=wv), same k-major layout =====
    if (wv <= 2) {
      const float* lptr = W_ih + (size_t)(wv * 512 + j * 64 + r8) * Cn + c8 * 4;
      const double4* x4 = (const double4*)s_x;
      double acc[8];
#pragma unroll
      for (int b = 0; b < 8; ++b) acc[b] = 0.;
#pragma unroll
      for (int kk = 0; kk < 4; ++kk) {
        const double4 xv = x4[kk * 8 + c8];
#pragma unroll
        for (int b = 0; b < 8; ++b) {
          const float4 w = *(const float4*)(lptr + (size_t)b * 8 * Cn + kk * 32);
          acc[b] = fma((double)w.x, xv.x, acc[b]);
          acc[b] = fma((double)w.y, xv.y, acc[b]);
          acc[b] = fma((double)w.z, xv.z, acc[b]);
          acc[b] = fma((double)w.w, xv.w, acc[b]);
        }
      }
#pragma unroll
      for (int b = 0; b < 8; ++b) {
        acc[b] += __shfl_xor(acc[b], 1, 64);
        acc[b] += __shfl_xor(acc[b], 2, 64);
        acc[b] += __shfl_xor(acc[b], 4, 64);
        if (c8 == 0) s_xg[wv][b * 8 + r8] = acc[b];
      }
    }
    __syncthreads();

    // ===== combine (wave 0) -> h_{t+1} slice (r3-proven structure) =====
    if (wv == 0) {
      double hr = s_hg[0][lane] + bhh_r;
      double hz = s_hg[1][lane] + bhh_z;
      double hn = s_hg[2][lane] + bhh_n;
      double xr = s_xg[0][lane] + bih_r;
      double xz = s_xg[1][lane] + bih_z;
      double xn = s_xg[2][lane] + bih_n;
      double r = 1.0 / (1.0 + exp(-(xr + hr)));
      double z = 1.0 / (1.0 + exp(-(xz + hz)));
      double n = tanh(xn + r * hn);
      double hv = (1.0 - z) * n + z * s_h[j * 64 + lane];
      st_d(&hnxt[j * 64 + lane], hv);
    }
    gar(ctrH);
    gwt(ctrH, (unsigned)(8 * (t + 2)));
    ((d2_t*)s_h)[tid] = ld_d2(hnxt + 2 * tid);   // s_h = h_{t+1}
    __syncthreads();
    if (t == Tn - 1 && j == 0) {
      out[OUT_HF + (size_t)g * Gn + tid] = (float)s_h[tid];
      out[OUT_HF + (size_t)g * Gn + tid + 256] = (float)s_h[tid + 256];
    }

    // ===== B: hid slice (each wave: 16 rows, full k) =====
    {
      const float* lptr = W_hid
          + (size_t)(j * 64 + wv * 16 + r8) * Gn + c8 * 4;
      const double4* h4 = (const double4*)s_h;
      double acc[2];
      acc[0] = 0.; acc[1] = 0.;
#pragma unroll 4
      for (int kk = 0; kk < 16; ++kk) {
        const double4 hv = h4[kk * 8 + c8];
#pragma unroll
        for (int b = 0; b < 2; ++b) {
          const float4 w = *(const float4*)(lptr + (size_t)b * 8 * Gn + kk * 32);
          acc[b] = fma((double)w.x, hv.x, acc[b]);
          acc[b] = fma((double)w.y, hv.y, acc[b]);
          acc[b] = fma((double)w.z, hv.z, acc[b]);
          acc[b] = fma((double)w.w, hv.w, acc[b]);
        }
      }
#pragma unroll
      for (int b = 0; b < 2; ++b) {
        acc[b] += __shfl_xor(acc[b], 1, 64);
        acc[b] += __shfl_xor(acc[b], 2, 64);
        acc[b] += __shfl_xor(acc[b], 4, 64);
        if (c8 == 0) s_hidraw[wv * 16 + b * 8 + r8] = acc[b];
      }
    }
    __syncthreads();
    if (tid < 64) {
      double acc = s_hidraw[tid] + (double)b_hid[j * 64 + tid];
      s_hid[tid] = acc > 0.0 ? acc : 0.0;
    }
    __syncthreads();
    // ===== partial logits: each wave 64 v-rows, k = j-slice of 64 =====
    {
      const float* lptr = W_out
          + (size_t)(wv * 64 + r8) * Hn + j * 64 + c8 * 4;
      const double4* hh = (const double4*)s_hid;
      double acc[8];
#pragma unroll
      for (int b = 0; b < 8; ++b) acc[b] = 0.;
#pragma unroll
      for (int kk = 0; kk < 2; ++kk) {
        const double4 hv = hh[kk * 8 + c8];
#pragma unroll
        for (int b = 0; b < 8; ++b) {
          const float4 w = *(const float4*)(lptr + (size_t)b * 8 * Hn + kk * 32);
          acc[b] = fma((double)w.x, hv.x, acc[b]);
          acc[b] = fma((double)w.y, hv.y, acc[b]);
          acc[b] = fma((double)w.z, hv.z, acc[b]);
          acc[b] = fma((double)w.w, hv.w, acc[b]);
        }
      }
#pragma unroll
      for (int b = 0; b < 8; ++b) {
        acc[b] += __shfl_xor(acc[b], 1, 64);
        acc[b] += __shfl_xor(acc[b], 2, 64);
        acc[b] += __shfl_xor(acc[b], 4, 64);
        if (c8 == 0) st_d(&PL[j * 256 + wv * 64 + b * 8 + r8], acc[b]);
      }
    }
    gar(ctrP);
  }

  // ===== final resolve: step Tn-1 =====
  gwt(ctrP, (unsigned)(8 * Tn));
  {
    const int v = tid;
    double l[8];
    ld8(PL, v, l);
    double logit = ((((((((l[0] + l[1]) + l[2]) + l[3]) + l[4]) + l[5])
                     + l[6]) + l[7])) + bout_reg;
    if (j == 0)
      out[(size_t)g * Tn * Vn + (size_t)(Tn - 1) * Vn + v] = (float)logit;
    unsigned kt0, kt1;
    threefry2x32(0u, 1u, 0u, (unsigned)(Tn - 1), kt0, kt1);
    double gum = jax_gumbel(kt0, kt1, (unsigned)(g * Vn + v));
    double bv = logit + gum;
    int bi = v;
#pragma unroll
    for (int off = 1; off < 64; off <<= 1) {
      double ov = __shfl_xor(bv, off, 64);
      int oi = __shfl_xor(bi, off, 64);
      if (ov > bv || (ov == bv && oi < bi)) { bv = ov; bi = oi; }
    }
    if (lane == 0) { s_pv[wv] = bv; s_pi[wv] = bi; }
    __syncthreads();
    double fv = s_pv[0]; int fi = s_pi[0];
#pragma unroll
    for (int w = 1; w < 4; ++w) {
      double ov = s_pv[w]; int oi = s_pi[w];
      if (ov > fv || (ov == fv && oi < fi)) { fv = ov; fi = oi; }
    }
    if (tid == 0 && j == 0)
      out[OUT_SAMP + (size_t)g * Tn + (Tn - 1)] = (float)fi;
  }
}

extern "C" void kernel_launch(void* const* d_in, const int* in_sizes, int n_in,
                              void* d_out, int out_size, void* d_ws, size_t ws_size,
                              hipStream_t stream) {
  const float* cond  = (const float*)d_in[0];
  const float* h0    = (const float*)d_in[1];
  const float* W_ih  = (const float*)d_in[2];
  const float* W_hh  = (const float*)d_in[3];
  const float* b_ih  = (const float*)d_in[4];
  const float* b_hh  = (const float*)d_in[5];
  const float* W_hid = (const float*)d_in[6];
  const float* b_hid = (const float*)d_in[7];
  const float* W_out = (const float*)d_in[8];
  const float* b_out = (const float*)d_in[9];
  const float* emb   = (const float*)d_in[10];

  // zero the counter region (ws is poisoned 0xAA before every call)
  hipMemsetAsync(d_ws, 0, 4096, stream);
  hipLaunchKernelGGL(wavernn_pipe, dim3(NBLK), dim3(NTHR), 0, stream,
                     cond, h0, W_ih, W_hh, b_ih, b_hh, W_hid, b_hid,
                     W_out, b_out, emb, (float*)d_out, (double*)d_ws);
}

// Round 7
// 45171.948 us; speedup vs baseline: 1.3021x; 1.3021x over previous
//
#include <hip/hip_runtime.h>
#include <stdint.h>
#include <math.h>

#define NBLK 128
#define NTHR 256
#define Bn 16
#define Tn 2000
#define Cn 128
#define Gn 512
#define Hn 512
#define Vn 256

// ws layout (doubles, after 4096B reserved header kept for compat):
// per group g (stride 6144 doubles from WS_DBL_BASE):
//   Hb0: 512 (value,stamp) pairs = 1024 dbl   h buffers, stamp = step+1
//   Hb1: 1024 dbl
//   PLp: 8 slots x 256 (value,stamp) pairs = 4096 dbl, stamp = t+1 for PL_t
// Stamped pairs are self-publishing: one 16B store both writes and
// publishes a datum; consumers poll the pair itself. No flags/counters.
#define WS_DBL_BASE 512
#define GRP_STRIDE  6144

#define OUT_SAMP ((size_t)Bn*Tn*Vn)          // 8,192,000
#define OUT_HF   (OUT_SAMP + (size_t)Bn*Tn)  // 8,224,000

typedef __attribute__((ext_vector_type(2))) double d2_t;

__device__ __forceinline__ unsigned rotl32(unsigned v, int n) {
  return (v << n) | (v >> (32 - n));
}

// JAX threefry2x32, 20 rounds, exact.
__device__ __forceinline__ void threefry2x32(unsigned k0, unsigned k1,
                                             unsigned c0, unsigned c1,
                                             unsigned& o0, unsigned& o1) {
  unsigned ks2 = k0 ^ k1 ^ 0x1BD11BDAu;
  unsigned x0 = c0 + k0;
  unsigned x1 = c1 + k1;
#define TF_R(r) { x0 += x1; x1 = rotl32(x1, r); x1 ^= x0; }
  TF_R(13) TF_R(15) TF_R(26) TF_R(6)
  x0 += k1;  x1 += ks2 + 1u;
  TF_R(17) TF_R(29) TF_R(16) TF_R(24)
  x0 += ks2; x1 += k0 + 2u;
  TF_R(13) TF_R(15) TF_R(26) TF_R(6)
  x0 += k0;  x1 += k1 + 3u;
  TF_R(17) TF_R(29) TF_R(16) TF_R(24)
  x0 += k1;  x1 += ks2 + 4u;
  TF_R(13) TF_R(15) TF_R(26) TF_R(6)
  x0 += ks2; x1 += k0 + 5u;
#undef TF_R
  o0 = x0; o1 = x1;
}

// exact JAX partitionable gumbel for step key (kt0,kt1), flat index f
__device__ __forceinline__ double jax_gumbel(unsigned kt0, unsigned kt1,
                                             unsigned f) {
  unsigned r0, r1;
  threefry2x32(kt0, kt1, 0u, f, r0, r1);
  unsigned bits = r0 ^ r1;
  float uf = __uint_as_float((bits >> 9) | 0x3f800000u) - 1.0f;
  if (uf <= 0.f) uf = 1.17549435e-38f;  // np.finfo(float32).tiny
  return -log(-log((double)uf));
}

// ---- stamped-pair comm primitives: system scope (sc0 sc1), PROVEN semantics.
// (r1/r4 measured: narrower scopes are NOT coherent for 8-block groups.)
// All multi-load asm uses "=&v" early-clobber (r2 lesson) and "memory"
// clobber on poll loads so the compiler cannot cache across retries.
__device__ __forceinline__ void stp(double* p, double v, double s) {
  d2_t d; d.x = v; d.y = s;
  asm volatile("global_store_dwordx4 %0, %1, off sc0 sc1"
               :: "v"(p), "v"(d) : "memory");
}
// two adjacent pairs (32B) with a single wait
__device__ __forceinline__ void ldp2(const double* p, d2_t& a, d2_t& b) {
  asm volatile("global_load_dwordx4 %0, %2, off sc0 sc1\n\t"
               "global_load_dwordx4 %1, %2, off offset:16 sc0 sc1\n\t"
               "s_waitcnt vmcnt(0)"
               : "=&v"(a), "=&v"(b) : "v"(p) : "memory");
}
// 8 pairs at arbitrary addresses with a single wait (PL gather)
__device__ __forceinline__ void ldp8(const double* p0, const double* p1,
                                     const double* p2, const double* p3,
                                     const double* p4, const double* p5,
                                     const double* p6, const double* p7,
                                     d2_t* r) {
  d2_t r0, r1, r2, r3, r4, r5, r6, r7;
  asm volatile(
    "global_load_dwordx4 %[o0], %[a0], off sc0 sc1\n\t"
    "global_load_dwordx4 %[o1], %[a1], off sc0 sc1\n\t"
    "global_load_dwordx4 %[o2], %[a2], off sc0 sc1\n\t"
    "global_load_dwordx4 %[o3], %[a3], off sc0 sc1\n\t"
    "global_load_dwordx4 %[o4], %[a4], off sc0 sc1\n\t"
    "global_load_dwordx4 %[o5], %[a5], off sc0 sc1\n\t"
    "global_load_dwordx4 %[o6], %[a6], off sc0 sc1\n\t"
    "global_load_dwordx4 %[o7], %[a7], off sc0 sc1\n\t"
    "s_waitcnt vmcnt(0)"
    : [o0]"=&v"(r0), [o1]"=&v"(r1), [o2]"=&v"(r2), [o3]"=&v"(r3),
      [o4]"=&v"(r4), [o5]"=&v"(r5), [o6]"=&v"(r6), [o7]"=&v"(r7)
    : [a0]"v"(p0), [a1]"v"(p1), [a2]"v"(p2), [a3]"v"(p3),
      [a4]"v"(p4), [a5]"v"(p5), [a6]"v"(p6), [a7]"v"(p7)
    : "memory");
  r[0]=r0; r[1]=r1; r[2]=r2; r[3]=r3; r[4]=r4; r[5]=r5; r[6]=r6; r[7]=r7;
}

extern "C" __global__ __launch_bounds__(NTHR)
void wavernn_pipe(const float* __restrict__ cond, const float* __restrict__ h0,
                  const float* __restrict__ W_ih, const float* __restrict__ W_hh,
                  const float* __restrict__ b_ih, const float* __restrict__ b_hh,
                  const float* __restrict__ W_hid, const float* __restrict__ b_hid,
                  const float* __restrict__ W_out, const float* __restrict__ b_out,
                  const float* __restrict__ emb,
                  float* __restrict__ out, double* __restrict__ ws) {
  const int tid = threadIdx.x;
  const int blk = blockIdx.x;
  const int g = blk >> 3;   // batch element (group)
  const int j = blk & 7;    // slot; slot-major => weight slice j is XCD-local
  const int lane = tid & 63, wv = tid >> 6;

  double* G   = ws + WS_DBL_BASE + (size_t)g * GRP_STRIDE;
  double* Hb0 = G;            // 512 pairs
  double* Hb1 = G + 1024;     // 512 pairs
  double* PLp = G + 2048;     // 8*256 pairs

  __shared__ __attribute__((aligned(32))) double s_x[Cn];
  __shared__ __attribute__((aligned(32))) double s_h[Gn];
  __shared__ __attribute__((aligned(32))) double s_hid[64];
  __shared__ double s_hn[64], s_in[64], s_z[64];
  __shared__ double s_part[4][64];
  __shared__ double s_gum[256];
  __shared__ float  s_cond[Cn];
  __shared__ double s_pv[4];
  __shared__ int    s_pi[4];

  const double bout_reg = (double)b_out[tid];

  // PL gather addresses for this thread (v = tid), slot s at s*512 doubles
  const double* plA0 = PLp + 2 * tid;
  const double* plA1 = plA0 + 512;
  const double* plA2 = plA0 + 1024;
  const double* plA3 = plA0 + 1536;
  const double* plA4 = plA0 + 2048;
  const double* plA5 = plA0 + 2560;
  const double* plA6 = plA0 + 3072;
  const double* plA7 = plA0 + 3584;

  // ---- init: H0 slice <- h0 (stamped 1.0); x0 = cond[:,0,:] + emb[128] ----
  if (tid < 64) stp(&Hb0[2 * (j * 64 + tid)],
                    (double)h0[(size_t)g * Gn + j * 64 + tid], 1.0);
  if (tid < Cn) s_x[tid] = (double)cond[(size_t)g * Tn * Cn + tid]
                         + (double)emb[128 * Cn + tid];
  {
    d2_t a, b; int guard = 0;
    do { ldp2(Hb0 + 4 * tid, a, b); }
    while ((a.y != 1.0 || b.y != 1.0) && ++guard < 2000000);
    s_h[2 * tid] = a.x; s_h[2 * tid + 1] = b.x;
  }
  __syncthreads();

  for (int t = 0; t < Tn; ++t) {
    double* hnxt = (t & 1) ? Hb0 : Hb1;       // pair buffer for h_{t+1}

    // ===== WINDOW (overlaps in-flight PL_{t-1} stores) =====
    double ha0 = 0., ha1 = 0., ha2 = 0., ha3 = 0.;
    if (wv <= 2) {
      const int row = wv * 512 + j * 64 + lane;   // r(0) z(1) hn(2) rows
      const float4* wh = (const float4*)(W_hh + (size_t)row * Gn);
      const double4* h4 = (const double4*)s_h;
#pragma unroll 8
      for (int k = 0; k < Gn / 4; ++k) {
        float4 w = wh[k]; double4 hv = h4[k];
        ha0 = fma((double)w.x, hv.x, ha0); ha1 = fma((double)w.y, hv.y, ha1);
        ha2 = fma((double)w.z, hv.z, ha2); ha3 = fma((double)w.w, hv.w, ha3);
      }
      if (wv == 2)
        s_hn[lane] = ((ha0 + ha1) + (ha2 + ha3)) + (double)b_hh[row];
    } else {
      // wave 3: stage cond[:,t,:] ; gumbel for step t-1 (consumed at resolve)
      const int c0 = 2 * lane;
      s_cond[c0]     = cond[((size_t)g * Tn + t) * Cn + c0];
      s_cond[c0 + 1] = cond[((size_t)g * Tn + t) * Cn + c0 + 1];
      if (t > 0) {
        unsigned kt0, kt1;
        threefry2x32(0u, 1u, 0u, (unsigned)(t - 1), kt0, kt1);
#pragma unroll
        for (int i = 0; i < 4; ++i) {
          int v = 4 * lane + i;
          s_gum[v] = jax_gumbel(kt0, kt1, (unsigned)(g * Vn + v));
        }
      }
    }

    // ===== PL poll + resolve of step t-1 =====
    if (t > 0) {
      const double exP = (double)t;   // PL_{t-1} stamped t
      double l[8];
      {
        d2_t r[8]; int guard = 0;
        for (;;) {
          ldp8(plA0, plA1, plA2, plA3, plA4, plA5, plA6, plA7, r);
          bool ok = (r[0].y == exP) & (r[1].y == exP) & (r[2].y == exP)
                  & (r[3].y == exP) & (r[4].y == exP) & (r[5].y == exP)
                  & (r[6].y == exP) & (r[7].y == exP);
          if (ok || ++guard > 2000000) {
            l[0]=r[0].x; l[1]=r[1].x; l[2]=r[2].x; l[3]=r[3].x;
            l[4]=r[4].x; l[5]=r[5].x; l[6]=r[6].x; l[7]=r[7].x;
            break;
          }
        }
      }
      const int v = tid;
      double logit = ((((((((l[0] + l[1]) + l[2]) + l[3]) + l[4]) + l[5])
                       + l[6]) + l[7])) + bout_reg;
      if (j == 0)
        out[(size_t)g * Tn * Vn + (size_t)(t - 1) * Vn + v] = (float)logit;
      double bv = logit + s_gum[v];
      int bi = v;
#pragma unroll
      for (int off = 1; off < 64; off <<= 1) {
        double ov = __shfl_xor(bv, off, 64);
        int oi = __shfl_xor(bi, off, 64);
        if (ov > bv || (ov == bv && oi < bi)) { bv = ov; bi = oi; }
      }
      if (lane == 0) { s_pv[wv] = bv; s_pi[wv] = bi; }
      __syncthreads();
      double fv = s_pv[0]; int fi = s_pi[0];
#pragma unroll
      for (int w = 1; w < 4; ++w) {
        double ov = s_pv[w]; int oi = s_pi[w];
        if (ov > fv || (ov == fv && oi < fi)) { fv = ov; fi = oi; }
      }
      const int samp = fi;
      if (tid == 0 && j == 0)
        out[OUT_SAMP + (size_t)g * Tn + (t - 1)] = (float)samp;
      if (tid < Cn)
        s_x[tid] = (double)s_cond[tid] + (double)emb[(size_t)samp * Cn + tid];
      __syncthreads();
    } else {
      __syncthreads();  // order window LDS writes vs x-phase reads
    }

    // ===== x-phase: x-dots + sigmoids =====
    double r_reg = 0.;
    if (wv <= 1) {
      const int row = wv * 512 + j * 64 + lane;
      const float4* wi = (const float4*)(W_ih + (size_t)row * Cn);
      const double4* x4 = (const double4*)s_x;
      double xa0 = 0., xa1 = 0., xa2 = 0., xa3 = 0.;
#pragma unroll 8
      for (int k = 0; k < Cn / 4; ++k) {
        float4 w = wi[k]; double4 xv = x4[k];
        xa0 = fma((double)w.x, xv.x, xa0); xa1 = fma((double)w.y, xv.y, xa1);
        xa2 = fma((double)w.z, xv.z, xa2); xa3 = fma((double)w.w, xv.w, xa3);
      }
      double gi = ((xa0 + xa1) + (xa2 + xa3)) + (double)b_ih[row];
      double gh = ((ha0 + ha1) + (ha2 + ha3)) + (double)b_hh[row];
      double pre = gi + gh;
      double sig = 1.0 / (1.0 + exp(-pre));
      if (wv == 0) r_reg = sig; else s_z[lane] = sig;
    } else if (wv == 3) {
      const int row = 1024 + j * 64 + lane;
      const float4* wi = (const float4*)(W_ih + (size_t)row * Cn);
      const double4* x4 = (const double4*)s_x;
      double a0 = 0., a1 = 0., a2 = 0., a3 = 0.;
#pragma unroll 8
      for (int k = 0; k < Cn / 4; ++k) {
        float4 w = wi[k]; double4 xv = x4[k];
        a0 = fma((double)w.x, xv.x, a0); a1 = fma((double)w.y, xv.y, a1);
        a2 = fma((double)w.z, xv.z, a2); a3 = fma((double)w.w, xv.w, a3);
      }
      s_in[lane] = ((a0 + a1) + (a2 + a3)) + (double)b_ih[row];
    }
    __syncthreads();

    // ===== combine (wave 0) -> h_{t+1} slice, stamped (t+2) =====
    if (wv == 0) {
      double z = s_z[lane];
      double n = tanh(s_in[lane] + r_reg * s_hn[lane]);
      double hv = (1.0 - z) * n + z * s_h[j * 64 + lane];
      stp(&hnxt[2 * (j * 64 + lane)], hv, (double)(t + 2));
    }
    __syncthreads();   // all reads of old s_h done before poll overwrites it
    {
      const double exH = (double)(t + 2);
      d2_t a, b; int guard = 0;
      do { ldp2(hnxt + 4 * tid, a, b); }
      while ((a.y != exH || b.y != exH) && ++guard < 2000000);
      s_h[2 * tid] = a.x; s_h[2 * tid + 1] = b.x;
    }
    __syncthreads();
    if (t == Tn - 1 && j == 0) {
      out[OUT_HF + (size_t)g * Gn + tid] = (float)s_h[tid];
      out[OUT_HF + (size_t)g * Gn + tid + 256] = (float)s_h[tid + 256];
    }

    // ===== B: hid slice + partial logits (stamped t+1) =====
    {
      const int row = j * 64 + lane;          // q = wv (wave-uniform)
      const float4* wr = (const float4*)(W_hid + (size_t)row * Gn + wv * 128);
      const double4* hh = (const double4*)(s_h + wv * 128);
      double a0 = 0., a1 = 0., a2 = 0., a3 = 0.;
#pragma unroll 8
      for (int k = 0; k < 32; ++k) {
        float4 w = wr[k]; double4 hv = hh[k];
        a0 = fma((double)w.x, hv.x, a0); a1 = fma((double)w.y, hv.y, a1);
        a2 = fma((double)w.z, hv.z, a2); a3 = fma((double)w.w, hv.w, a3);
      }
      s_part[wv][lane] = (a0 + a1) + (a2 + a3);
    }
    __syncthreads();
    if (tid < 64) {
      double acc = (s_part[0][tid] + s_part[1][tid])
                 + (s_part[2][tid] + s_part[3][tid])
                 + (double)b_hid[j * 64 + tid];
      s_hid[tid] = acc > 0.0 ? acc : 0.0;
    }
    __syncthreads();
    {
      const int v = tid;
      const float4* wr = (const float4*)(W_out + (size_t)v * Hn + j * 64);
      const double4* hh = (const double4*)s_hid;
      double a0 = 0., a1 = 0., a2 = 0., a3 = 0.;
#pragma unroll 8
      for (int k = 0; k < 16; ++k) {
        float4 w = wr[k]; double4 hv = hh[k];
        a0 = fma((double)w.x, hv.x, a0); a1 = fma((double)w.y, hv.y, a1);
        a2 = fma((double)w.z, hv.z, a2); a3 = fma((double)w.w, hv.w, a3);
      }
      stp(&PLp[2 * (j * 256 + v)], (a0 + a1) + (a2 + a3), (double)(t + 1));
    }
    // no barrier: the stamped stores publish themselves
  }

  // ===== final resolve: step Tn-1 (PL stamped Tn) =====
  {
    const double exP = (double)Tn;
    double l[8];
    {
      d2_t r[8]; int guard = 0;
      for (;;) {
        ldp8(plA0, plA1, plA2, plA3, plA4, plA5, plA6, plA7, r);
        bool ok = (r[0].y == exP) & (r[1].y == exP) & (r[2].y == exP)
                & (r[3].y == exP) & (r[4].y == exP) & (r[5].y == exP)
                & (r[6].y == exP) & (r[7].y == exP);
        if (ok || ++guard > 2000000) {
          l[0]=r[0].x; l[1]=r[1].x; l[2]=r[2].x; l[3]=r[3].x;
          l[4]=r[4].x; l[5]=r[5].x; l[6]=r[6].x; l[7]=r[7].x;
          break;
        }
      }
    }
    const int v = tid;
    double logit = ((((((((l[0] + l[1]) + l[2]) + l[3]) + l[4]) + l[5])
                     + l[6]) + l[7])) + bout_reg;
    if (j == 0)
      out[(size_t)g * Tn * Vn + (size_t)(Tn - 1) * Vn + v] = (float)logit;
    unsigned kt0, kt1;
    threefry2x32(0u, 1u, 0u, (unsigned)(Tn - 1), kt0, kt1);
    double gum = jax_gumbel(kt0, kt1, (unsigned)(g * Vn + v));
    double bv = logit + gum;
    int bi = v;
#pragma unroll
    for (int off = 1; off < 64; off <<= 1) {
      double ov = __shfl_xor(bv, off, 64);
      int oi = __shfl_xor(bi, off, 64);
      if (ov > bv || (ov == bv && oi < bi)) { bv = ov; bi = oi; }
    }
    if (lane == 0) { s_pv[wv] = bv; s_pi[wv] = bi; }
    __syncthreads();
    double fv = s_pv[0]; int fi = s_pi[0];
#pragma unroll
    for (int w = 1; w < 4; ++w) {
      double ov = s_pv[w]; int oi = s_pi[w];
      if (ov > fv || (ov == fv && oi < fi)) { fv = ov; fi = oi; }
    }
    if (tid == 0 && j == 0)
      out[OUT_SAMP + (size_t)g * Tn + (Tn - 1)] = (float)fi;
  }
}

extern "C" void kernel_launch(void* const* d_in, const int* in_sizes, int n_in,
                              void* d_out, int out_size, void* d_ws, size_t ws_size,
                              hipStream_t stream) {
  const float* cond  = (const float*)d_in[0];
  const float* h0    = (const float*)d_in[1];
  const float* W_ih  = (const float*)d_in[2];
  const float* W_hh  = (const float*)d_in[3];
  const float* b_ih  = (const float*)d_in[4];
  const float* b_hh  = (const float*)d_in[5];
  const float* W_hid = (const float*)d_in[6];
  const float* b_hid = (const float*)d_in[7];
  const float* W_out = (const float*)d_in[8];
  const float* b_out = (const float*)d_in[9];
  const float* emb   = (const float*)d_in[10];

  // header kept zeroed (unused by the stamped protocol; stamps never
  // collide with the 0xAA poison pattern, so no other init is needed)
  hipMemsetAsync(d_ws, 0, 4096, stream);
  hipLaunchKernelGGL(wavernn_pipe, dim3(NBLK), dim3(NTHR), 0, stream,
                     cond, h0, W_ih, W_hh, b_ih, b_hh, W_hid, b_hid,
                     W_out, b_out, emb, (float*)d_out, (double*)d_ws);
}